// Round 1
// 2537.460 us; speedup vs baseline: 1.1543x; 1.1543x over previous
//
#include <hip/hip_runtime.h>
#include <hip/hip_bf16.h>
#include <stdint.h>

#define E_ 8
#define C_ 2048
#define D_ 2048
#define F_ 8192

typedef __bf16 bf16x8 __attribute__((ext_vector_type(8)));
typedef float floatx4 __attribute__((ext_vector_type(4)));
typedef uint32_t uint32x4 __attribute__((ext_vector_type(4)));

__device__ __forceinline__ uint16_t f2bf_rne(float f) {
    uint32_t u = __builtin_bit_cast(uint32_t, f);
    u += 0x7fffu + ((u >> 16) & 1u);
    return (uint16_t)(u >> 16);
}

__device__ __forceinline__ float gelu_tanh(float x) {
    // JAX default gelu (approximate=True): 0.5x(1+tanh(0.79788456(x+0.044715x^3)))
    float z = 0.7978845608028654f * x * (1.0f + 0.044715f * x * x);
    float e = __expf(2.0f * z);
    float t = 1.0f - 2.0f / (e + 1.0f);
    return 0.5f * x * (1.0f + t);
}

// ---------------- X: fp32 -> bf16, 8 elems/thread ----------------
__global__ __launch_bounds__(256) void convert_x_kernel(const float* __restrict__ in,
                                                        uint16_t* __restrict__ out, int n8) {
    int i = blockIdx.x * 256 + threadIdx.x;
    if (i >= n8) return;
    const floatx4* pin = (const floatx4*)in;
    floatx4 a = pin[2 * i];
    floatx4 b = pin[2 * i + 1];
    uint32x4 w;
    w[0] = (uint32_t)f2bf_rne(a[0]) | ((uint32_t)f2bf_rne(a[1]) << 16);
    w[1] = (uint32_t)f2bf_rne(a[2]) | ((uint32_t)f2bf_rne(a[3]) << 16);
    w[2] = (uint32_t)f2bf_rne(b[0]) | ((uint32_t)f2bf_rne(b[1]) << 16);
    w[3] = (uint32_t)f2bf_rne(b[2]) | ((uint32_t)f2bf_rne(b[3]) << 16);
    ((uint32x4*)out)[i] = w;
}

// ---------------- per-expert [K,N] fp32 -> [N,K] bf16 ----------------
__global__ __launch_bounds__(256) void transpose_convert_kernel(
    const float* __restrict__ in, uint16_t* __restrict__ out,
    int K, int N, int tiles_k, int tiles_n) {
    __shared__ float lds[64 * 65];
    int tiles = tiles_k * tiles_n;
    int e = blockIdx.x / tiles;
    int t = blockIdx.x % tiles;
    int tk = t % tiles_k;
    int tn = t / tiles_k;
    size_t ebase = (size_t)e * K * N;
    int k0 = tk * 64, n0 = tn * 64;
    const float* ip = in + ebase + (size_t)k0 * N + n0;
    int tid = threadIdx.x;
#pragma unroll
    for (int i = 0; i < 4; i++) {
        int lin = i * 256 + tid;
        int r = lin >> 4, c = lin & 15;
        floatx4 v = *(const floatx4*)(ip + (size_t)r * N + c * 4);
        float* l = &lds[r * 65 + c * 4];
        l[0] = v[0]; l[1] = v[1]; l[2] = v[2]; l[3] = v[3];
    }
    __syncthreads();
    uint16_t* op = out + ebase + (size_t)n0 * K + k0;
#pragma unroll
    for (int i = 0; i < 2; i++) {
        int lin = i * 256 + tid;
        int n = lin >> 3, c = lin & 7;
        uint32x4 w;
#pragma unroll
        for (int j = 0; j < 4; j++) {
            float f0 = lds[(c * 8 + 2 * j) * 65 + n];
            float f1 = lds[(c * 8 + 2 * j + 1) * 65 + n];
            w[j] = (uint32_t)f2bf_rne(f0) | ((uint32_t)f2bf_rne(f1) << 16);
        }
        *(uint32x4*)(op + (size_t)n * K + c * 8) = w;
    }
}

// ---------------- bf16 GEMM: C[M,N] = A[M,K] @ Bt[N,K]^T ----------------
// 128x128 tile / 256 threads (4 waves, each 64x64 = 4x4 of 16x16x32 MFMA).
// BK=32, TRIPLE-buffered LDS (48 KB -> 3 blocks/CU), depth-2 prefetch with
// counted s_waitcnt vmcnt(4) (never drains to 0 in the main loop), raw
// s_barrier (one per K-tile) + explicit lgkmcnt(0), setprio(1) around MFMAs.
// 64-B LDS row stride (BK=32) makes the fragment ds_read_b128 pattern
// bank-balanced with NO swizzle: bank quad = 4*(row&1) + (lane>>4), uniform
// 8 lanes per quad = structural floor.
//
// Race-freedom: K-tile t reads buf t%3; staging during t targets buf (t+2)%3
// only. Buf (t+2)%3 was last read at K-tile t-1, and every thread passes the
// t-1 boundary barrier only after its lgkmcnt(0) (its reads completed), so
// the stage issue cannot corrupt in-flight reads. Boundary vmcnt(4) leaves
// exactly the 4 just-issued loads (K-tile t+2) outstanding and guarantees
// K-tile t+1 (issued one K-tile earlier) has landed.
#define GLL16(gp, lp)                                                    \
    __builtin_amdgcn_global_load_lds(                                    \
        (const __attribute__((address_space(1))) uint32_t*)(gp),         \
        (__attribute__((address_space(3))) uint32_t*)(lp), 16, 0, 0)

template <int GELU>
__global__ __launch_bounds__(256, 3) void gemm_bt_kernel(
    const uint16_t* __restrict__ A,   // [E][M][K] bf16
    const uint16_t* __restrict__ Bt,  // [E][N][K] bf16
    const float* __restrict__ bias,   // [E][N]
    void* __restrict__ Out,           // [E][M][N] bf16 if GELU else fp32
    int M, int N, int K, int tiles_m, int tiles_n) {
    // per buf: A[128][32] at elems [0,4096), B[128][32] at elems [4096,8192)
    __shared__ __align__(16) uint16_t lds[3][8192];

    int tiles = tiles_m * tiles_n;
    int e = blockIdx.x / tiles;
    int t = blockIdx.x % tiles;
    int bm = t % tiles_m;   // m-fastest: consecutive blocks share the B tile (L2)
    int bn = t / tiles_m;
    int tid = threadIdx.x;
    int lane = tid & 63;
    int wid = tid >> 6;
    int wm = wid >> 1, wn = wid & 1;

    const uint16_t* Ae = A + (size_t)e * M * K;
    const uint16_t* Be = Bt + (size_t)e * N * K;

    // staging: per GLL a wave writes 512 elems = 16 rows x 32 k (linear).
    // lane covers row wid*16 + (lane>>2), k-chunk (lane&3)*8.
    int srow = wid * 16 + (lane >> 2);
    int scol = (lane & 3) * 8;
    const uint16_t* Ag = Ae + (size_t)(bm * 128 + srow) * K + scol;
    const uint16_t* Bg = Be + (size_t)(bn * 128 + srow) * K + scol;
    int ldsA = wid * 512;  // elems (wave-uniform base; HW adds lane*16B)

    // fragment read byte offsets (linear, conflict-free at 64-B row stride)
    int l15 = lane & 15, l4 = lane >> 4;
    int arow[4], brow[4];
#pragma unroll
    for (int i = 0; i < 4; i++) {
        arow[i] = (wm * 64 + i * 16 + l15) * 64 + l4 * 16;           // A region
        brow[i] = 8192 + (wn * 64 + i * 16 + l15) * 64 + l4 * 16;    // B region (+8192 B)
    }

    floatx4 acc[4][4];
#pragma unroll
    for (int i = 0; i < 4; i++)
#pragma unroll
        for (int j = 0; j < 4; j++)
#pragma unroll
            for (int r = 0; r < 4; r++) acc[i][j][r] = 0.0f;

    int NT = K >> 5;

    auto stage = [&](int buf, int s) {
        uint16_t* base = &lds[buf][0];
        size_t k0 = (size_t)s << 5;
        GLL16(Ag + k0,                  base + ldsA);           // A rows 0..63
        GLL16(Ag + (size_t)64 * K + k0, base + 2048 + ldsA);    // A rows 64..127
        GLL16(Bg + k0,                  base + 4096 + ldsA);    // B rows 0..63
        GLL16(Bg + (size_t)64 * K + k0, base + 6144 + ldsA);    // B rows 64..127
    };

    // prologue: stage K-tiles 0 and 1, wait for K0 (leave K1's 4 in flight)
    stage(0, 0);
    stage(1, 1);
    asm volatile("s_waitcnt vmcnt(4)" ::: "memory");
    __builtin_amdgcn_s_barrier();

    int cb = 0;
    for (int kt = 0; kt < NT; ++kt) {
        const char* bufp = (const char*)&lds[cb][0];
        bf16x8 fa[4], fb[4];
#pragma unroll
        for (int i = 0; i < 4; i++) fa[i] = *(const bf16x8*)(bufp + arow[i]);
#pragma unroll
        for (int j = 0; j < 4; j++) fb[j] = *(const bf16x8*)(bufp + brow[j]);

        if (kt + 2 < NT) {
            int pb = cb + 2; if (pb >= 3) pb -= 3;
            stage(pb, kt + 2);
        }

        // my ds_reads must be complete before I pass the boundary barrier
        // (so the next K-tile's stage into this buffer cannot race them)
        asm volatile("s_waitcnt lgkmcnt(0)" ::: "memory");
        __builtin_amdgcn_sched_barrier(0);

        __builtin_amdgcn_s_setprio(1);
#pragma unroll
        for (int i = 0; i < 4; i++)
#pragma unroll
            for (int j = 0; j < 4; j++)
                acc[i][j] = __builtin_amdgcn_mfma_f32_16x16x32_bf16(fa[i], fb[j], acc[i][j], 0, 0, 0);
        __builtin_amdgcn_s_setprio(0);

        // boundary: guarantee K-tile kt+1 landed; keep kt+2's 4 loads in flight
        if (kt < NT - 2) {
            asm volatile("s_waitcnt vmcnt(4)" ::: "memory");
            __builtin_amdgcn_s_barrier();
        } else if (kt == NT - 2) {
            asm volatile("s_waitcnt vmcnt(0)" ::: "memory");
            __builtin_amdgcn_s_barrier();
        }
        cb++; if (cb == 3) cb = 0;
    }

    // epilogue: C/D layout col=lane&15, row=(lane>>4)*4+r (m89-verified)
    int col0 = bn * 128 + wn * 64 + (lane & 15);
    int row0 = bm * 128 + wm * 64 + (lane >> 4) * 4;
    const float* be = bias + (size_t)e * N;
    if (GELU) {
        uint16_t* O = (uint16_t*)Out + (size_t)e * M * N;
#pragma unroll
        for (int j = 0; j < 4; j++) {
            int col = col0 + j * 16;
            float bv = be[col];
#pragma unroll
            for (int i = 0; i < 4; i++) {
                int row = row0 + i * 16;
#pragma unroll
                for (int r = 0; r < 4; r++) {
                    float v = acc[i][j][r] + bv;
                    O[(size_t)(row + r) * N + col] = f2bf_rne(gelu_tanh(v));
                }
            }
        }
    } else {
        float* O = (float*)Out + (size_t)e * M * N;
#pragma unroll
        for (int j = 0; j < 4; j++) {
            int col = col0 + j * 16;
            float bv = be[col];
#pragma unroll
            for (int i = 0; i < 4; i++) {
                int row = row0 + i * 16;
#pragma unroll
                for (int r = 0; r < 4; r++) {
                    O[(size_t)(row + r) * N + col] = acc[i][j][r] + bv;
                }
            }
        }
    }
}

extern "C" void kernel_launch(void* const* d_in, const int* in_sizes, int n_in,
                              void* d_out, int out_size, void* d_ws, size_t ws_size,
                              hipStream_t stream) {
    (void)in_sizes; (void)n_in; (void)out_size; (void)ws_size;
    const float* x  = (const float*)d_in[0];
    const float* w1 = (const float*)d_in[1];
    const float* b1 = (const float*)d_in[2];
    const float* w2 = (const float*)d_in[3];
    const float* b2 = (const float*)d_in[4];
    float* out = (float*)d_out;

    // workspace layout (bf16): Xb 64M, Wt 256M (W1t then reused for W2t), Hb 256M
    uint16_t* Xb = (uint16_t*)d_ws;                    // E*C*D
    uint16_t* Wt = Xb + (size_t)E_ * C_ * D_;          // max(E*D*F, E*F*D)
    uint16_t* Hb = Wt + (size_t)E_ * D_ * F_;          // E*C*F

    int n8 = (E_ * C_ * D_) / 8;
    convert_x_kernel<<<n8 / 256, 256, 0, stream>>>(x, Xb, n8);

    // W1 [E][D][F] -> W1t [E][F][D]
    transpose_convert_kernel<<<E_ * (D_ / 64) * (F_ / 64), 256, 0, stream>>>(
        w1, Wt, D_, F_, D_ / 64, F_ / 64);

    // H = gelu(X @ W1 + b1), bf16
    gemm_bt_kernel<1><<<E_ * (C_ / 128) * (F_ / 128), 256, 0, stream>>>(
        Xb, Wt, b1, Hb, C_, F_, D_, C_ / 128, F_ / 128);

    // W2 [E][F][D] -> W2t [E][D][F] (reuses Wt after GEMM1 completes; stream-serialized)
    transpose_convert_kernel<<<E_ * (F_ / 64) * (D_ / 64), 256, 0, stream>>>(
        w2, Wt, F_, D_, F_ / 64, D_ / 64);

    // Out = H @ W2 + b2, fp32
    gemm_bt_kernel<0><<<E_ * (C_ / 128) * (D_ / 128), 256, 0, stream>>>(
        Hb, Wt, b2, out, C_, D_, F_, C_ / 128, D_ / 128);
}